// Round 10
// baseline (251.800 us; speedup 1.0000x reference)
//
#include <hip/hip_runtime.h>

// WindowAttention, MI355X gfx950 — round 10.
// R9 minus the load-serialization: A-frags (x window) loaded ONCE per wave into
// registers (no prep_x pass, fp32->bf16 inline, 192 f2bs/wave); 4 waves of a
// block share ONE head (wT B-frag L1 reuse); launch_bounds(256,3) for pipelining.
// Attention numerics identical to R5/R8/R9 (absmax 9.8e-4 verified).

#define DIMC 192
#define NHEAD 6
#define HD 32
#define NTOK 49
#define NWIN 64
#define SCALE 0.17677669529663687f  // 1/sqrt(32)
#define SP 36                       // scratch pitch (shorts)
#define WSZ (49 * SP)               // 1764 shorts per wave

typedef short bf16x8 __attribute__((ext_vector_type(8)));
typedef short bf16x4 __attribute__((ext_vector_type(4)));
typedef float f32x4 __attribute__((ext_vector_type(4)));

__device__ __forceinline__ short f2bs(float f) {
    // round-to-nearest-even fp32 -> bf16
    unsigned u = __builtin_bit_cast(unsigned, f);
    u = (u + 0x7fffu + ((u >> 16) & 1u)) >> 16;
    return (short)(unsigned short)u;
}

// 8-bf16 fragment load from 8B-aligned LDS
__device__ __forceinline__ bf16x8 ld8(const short* p) {
    bf16x4 lo = *reinterpret_cast<const bf16x4*>(p);
    bf16x4 hi = *reinterpret_cast<const bf16x4*>(p + 4);
    return __builtin_shufflevector(lo, hi, 0, 1, 2, 3, 4, 5, 6, 7);
}

// 8 fp32 (two float4) -> bf16x8, RNE
__device__ __forceinline__ bf16x8 cvt8(const float4* p) {
    const float4 v0 = p[0], v1 = p[1];
    bf16x8 r;
    r[0] = f2bs(v0.x); r[1] = f2bs(v0.y); r[2] = f2bs(v0.z); r[3] = f2bs(v0.w);
    r[4] = f2bs(v1.x); r[5] = f2bs(v1.y); r[6] = f2bs(v1.z); r[7] = f2bs(v1.w);
    return r;
}

__global__ void prep_weights(const float* __restrict__ qkv_w,
                             const float* __restrict__ proj_w,
                             short* __restrict__ wT, short* __restrict__ pT) {
    int i = blockIdx.x * 256 + threadIdx.x;
    if (i < DIMC * 3 * DIMC) {  // qkv_w [192][576] -> wT [576][192] bf16
        int k = i / (3 * DIMC), c = i - k * (3 * DIMC);
        wT[c * DIMC + k] = f2bs(qkv_w[i]);
    }
    if (i < DIMC * DIMC) {      // proj_w [192][192] -> pT [192][192] bf16 (transposed)
        int k = i / DIMC, c = i - k * DIMC;
        pT[c * DIMC + k] = f2bs(proj_w[i]);
    }
}

// ---------------- Kernel A: QKV + attention ---------------------------------
// Block = 4 waves, wave wv handles (window wg*4+wv, head h). All waves share h.
__global__ __launch_bounds__(256, 3)
void qkv_attn(const float* __restrict__ x, const float* __restrict__ mask,
              const float* __restrict__ qkv_b, const short* __restrict__ wT,
              short* __restrict__ attn)
{
    __shared__ short smem[4 * WSZ];   // 14112 B
    const int wv = threadIdx.x >> 6;
    const int ln = threadIdx.x & 63;
    const int lr = ln & 15, lg = ln >> 4;
    // XCD swizzle (3072 % 8 == 0 -> bijective)
    const int chunkB = gridDim.x >> 3;
    const int logical = (blockIdx.x & 7) * chunkB + (blockIdx.x >> 3);
    const int wg = logical / NHEAD;           // window group (4 windows)
    const int h  = logical - wg * NHEAD;      // shared head for all 4 waves
    const int b  = wg * 4 + wv;
    short* const buf = smem + wv * WSZ;
    const float* xb = x + (long)b * NTOK * DIMC;

    // ---- load all 24 x A-frags ONCE (fp32 -> bf16 RNE, same bits as prep_x) --
    bf16x8 a[24];   // [kk*4+m]
    #pragma unroll
    for (int kk = 0; kk < 6; ++kk)
        #pragma unroll
        for (int m = 0; m < 4; ++m) {
            const int row = (m < 3) ? m * 16 + lr : 48;   // pad rows -> token-48 copy
            a[kk * 4 + m] = cvt8(reinterpret_cast<const float4*>(&xb[row * DIMC + kk * 32 + lg * 8]));
        }

    bf16x8 qa[4], kb[4], vb[2][2];

    // ---------- QKV: 3 chunks on resident A-frags, transposes via buf ----------
    {
        f32x4 acc[4][2];
        #pragma unroll
        for (int c = 0; c < 3; ++c) {
            const int c0 = c * DIMC + h * HD;
            #pragma unroll
            for (int m = 0; m < 4; ++m)
                #pragma unroll
                for (int n = 0; n < 2; ++n) acc[m][n] = f32x4{0.f, 0.f, 0.f, 0.f};
            __builtin_amdgcn_s_setprio(1);
            #pragma unroll
            for (int kk = 0; kk < 6; ++kk) {
                #pragma unroll
                for (int n = 0; n < 2; ++n) {
                    bf16x8 bw = *reinterpret_cast<const bf16x8*>(
                        &wT[(c0 + n * 16 + lr) * DIMC + kk * 32 + lg * 8]);
                    #pragma unroll
                    for (int m = 0; m < 4; ++m)
                        acc[m][n] = __builtin_amdgcn_mfma_f32_16x16x32_bf16(a[kk * 4 + m], bw, acc[m][n], 0, 0, 0);
                }
            }
            __builtin_amdgcn_s_setprio(0);

            if (c < 2) {
                // q or k -> buf [49][36] -> frags (lane=token, regs=feature)
                bf16x8* dst = c ? kb : qa;
                #pragma unroll
                for (int n2 = 0; n2 < 2; ++n2) {
                    const float bias = qkv_b[c * DIMC + h * HD + n2 * 16 + lr];
                    #pragma unroll
                    for (int m = 0; m < 3; ++m)
                        #pragma unroll
                        for (int r = 0; r < 4; ++r)
                            buf[(m * 16 + lg * 4 + r) * SP + n2 * 16 + lr] = f2bs(acc[m][n2][r] + bias);
                    if (lg == 0) buf[48 * SP + n2 * 16 + lr] = f2bs(acc[3][n2][0] + bias);  // row 48
                }
                #pragma unroll
                for (int m = 0; m < 3; ++m)
                    dst[m] = ld8(&buf[(m * 16 + lr) * SP + lg * 8]);
                dst[3] = ld8(&buf[48 * SP + lg * 8]);   // rows 48..63 -> token-48 copy
            } else {
                // v -> two sequential vT halves [32 d][SP] (tokens 0..31, 32..63)
                #pragma unroll
                for (int half = 0; half < 2; ++half) {
                    #pragma unroll
                    for (int n2 = 0; n2 < 2; ++n2) {
                        const float bias = qkv_b[2 * DIMC + h * HD + n2 * 16 + lr];
                        #pragma unroll
                        for (int mm = 0; mm < 2; ++mm) {
                            #pragma unroll
                            for (int r = 0; r < 4; ++r)
                                buf[(n2 * 16 + lr) * SP + mm * 16 + lg * 4 + r] =
                                    f2bs(acc[half * 2 + mm][n2][r] + bias);
                        }
                    }
                    #pragma unroll
                    for (int nb = 0; nb < 2; ++nb)
                        vb[half][nb] = ld8(&buf[(nb * 16 + lr) * SP + lg * 8]);
                }
            }
        }
    }

    // ---------- S = q k^T ----------
    f32x4 s[4][4];
    #pragma unroll
    for (int m = 0; m < 4; ++m)
        #pragma unroll
        for (int n = 0; n < 4; ++n) s[m][n] = f32x4{0.f, 0.f, 0.f, 0.f};
    __builtin_amdgcn_s_setprio(1);
    #pragma unroll
    for (int m = 0; m < 4; ++m)
        #pragma unroll
        for (int n = 0; n < 4; ++n)
            s[m][n] = __builtin_amdgcn_mfma_f32_16x16x32_bf16(qa[m], kb[n], s[m][n], 0, 0, 0);
    __builtin_amdgcn_s_setprio(0);

    // scale + mask + softmax WITHOUT max-subtraction (logits bounded)
    const float* mrow = mask + (long)(b & (NWIN - 1)) * NTOK * NTOK;
    float rinv[4][4];
    #pragma unroll
    for (int m = 0; m < 4; ++m)
        #pragma unroll
        for (int n = 0; n < 4; ++n) {
            const int col = n * 16 + lr;
            #pragma unroll
            for (int r = 0; r < 4; ++r) {
                const int row = m * 16 + lg * 4 + r;
                float v = s[m][n][r];
                v = (row < NTOK && col < NTOK) ? v * SCALE + mrow[row * NTOK + col] : -1e30f;
                s[m][n][r] = __expf(v);
            }
        }
    #pragma unroll
    for (int m = 0; m < 4; ++m)
        #pragma unroll
        for (int r = 0; r < 4; ++r) {
            float sum = s[m][0][r] + s[m][1][r] + s[m][2][r] + s[m][3][r];
            sum += __shfl_xor(sum, 1);
            sum += __shfl_xor(sum, 2);
            sum += __shfl_xor(sum, 4);
            sum += __shfl_xor(sum, 8);
            rinv[m][r] = 1.f / sum;
        }

    // ---------- PV via two UNNORMALIZED P halves in buf ----------
    f32x4 o[4][2];
    #pragma unroll
    for (int m = 0; m < 4; ++m)
        #pragma unroll
        for (int n = 0; n < 2; ++n) o[m][n] = f32x4{0.f, 0.f, 0.f, 0.f};
    #pragma unroll
    for (int half = 0; half < 2; ++half) {
        #pragma unroll
        for (int m = 0; m < 3; ++m)
            #pragma unroll
            for (int n2 = 0; n2 < 2; ++n2)
                #pragma unroll
                for (int r = 0; r < 4; ++r)
                    buf[(m * 16 + lg * 4 + r) * SP + n2 * 16 + lr] = f2bs(s[m][half * 2 + n2][r]);
        if (lg == 0) {
            #pragma unroll
            for (int n2 = 0; n2 < 2; ++n2)
                buf[48 * SP + n2 * 16 + lr] = f2bs(s[3][half * 2 + n2][0]);
        }
        bf16x8 pa[4];
        #pragma unroll
        for (int mi = 0; mi < 3; ++mi)
            pa[mi] = ld8(&buf[(mi * 16 + lr) * SP + lg * 8]);
        pa[3] = ld8(&buf[48 * SP + lg * 8]);
        __builtin_amdgcn_s_setprio(1);
        #pragma unroll
        for (int nb = 0; nb < 2; ++nb)
            #pragma unroll
            for (int mi = 0; mi < 4; ++mi)
                o[mi][nb] = __builtin_amdgcn_mfma_f32_16x16x32_bf16(pa[mi], vb[half][nb], o[mi][nb], 0, 0, 0);
        __builtin_amdgcn_s_setprio(0);
    }

    // ---------- store attn_out = o * rinv (bf16) -> d_ws ----------
    short* ab = attn + (long)b * NTOK * DIMC + h * HD;
    #pragma unroll
    for (int nb = 0; nb < 2; ++nb)
        #pragma unroll
        for (int m = 0; m < 4; ++m)
            #pragma unroll
            for (int r = 0; r < 4; ++r) {
                const int row = m * 16 + lg * 4 + r;
                if (row < NTOK)
                    ab[row * DIMC + nb * 16 + lr] = f2bs(o[m][nb][r] * rinv[m][r]);
            }
}

// ---------------- Kernel B: out = attn_out @ proj_w + proj_b ----------------
__global__ __launch_bounds__(256, 4)
void proj_gemm(const short* __restrict__ attn, const short* __restrict__ pT,
               const float* __restrict__ proj_b, float* __restrict__ out, long nrows)
{
    const int wv = threadIdx.x >> 6, ln = threadIdx.x & 63;
    const int lr = ln & 15, lg = ln >> 4;
    const long m0 = (long)blockIdx.x * 64;
    f32x4 acc[4][3];
    #pragma unroll
    for (int m = 0; m < 4; ++m)
        #pragma unroll
        for (int n = 0; n < 3; ++n) acc[m][n] = f32x4{0.f, 0.f, 0.f, 0.f};
    __builtin_amdgcn_s_setprio(1);
    #pragma unroll
    for (int kk = 0; kk < 6; ++kk) {
        const int k0 = kk * 32 + lg * 8;
        bf16x8 a[4];
        #pragma unroll
        for (int m = 0; m < 4; ++m) {
            long row = m0 + m * 16 + lr;
            if (row >= nrows) row = nrows - 1;
            a[m] = *reinterpret_cast<const bf16x8*>(&attn[row * DIMC + k0]);
        }
        #pragma unroll
        for (int n = 0; n < 3; ++n) {
            const int c = wv * 48 + n * 16 + lr;
            bf16x8 bw = *reinterpret_cast<const bf16x8*>(&pT[c * DIMC + k0]);
            #pragma unroll
            for (int m = 0; m < 4; ++m)
                acc[m][n] = __builtin_amdgcn_mfma_f32_16x16x32_bf16(a[m], bw, acc[m][n], 0, 0, 0);
        }
    }
    __builtin_amdgcn_s_setprio(0);
    #pragma unroll
    for (int n = 0; n < 3; ++n) {
        const int c = wv * 48 + n * 16 + lr;
        const float pb = proj_b[c];
        #pragma unroll
        for (int m = 0; m < 4; ++m)
            #pragma unroll
            for (int r = 0; r < 4; ++r) {
                const long row = m0 + m * 16 + lg * 4 + r;
                if (row < nrows) out[row * DIMC + c] = acc[m][n][r] + pb;
            }
    }
}

extern "C" void kernel_launch(void* const* d_in, const int* in_sizes, int n_in,
                              void* d_out, int out_size, void* d_ws, size_t ws_size,
                              hipStream_t stream) {
    const float* x      = (const float*)d_in[0];
    const float* mask   = (const float*)d_in[1];
    const float* qkv_w  = (const float*)d_in[2];
    const float* qkv_b  = (const float*)d_in[3];
    const float* proj_w = (const float*)d_in[4];
    const float* proj_b = (const float*)d_in[5];
    float* out = (float*)d_out;

    const int nwin = in_sizes[0] / (NTOK * DIMC);  // 2048
    const long nrows = (long)nwin * NTOK;          // 100352

    short* wT   = (short*)d_ws;                    // 576*192
    short* pT   = wT + DIMC * 3 * DIMC;            // 192*192
    short* attn = pT + DIMC * DIMC;                // nrows*192 bf16 (~38.5 MB)

    prep_weights<<<(DIMC * 3 * DIMC + 255) / 256, 256, 0, stream>>>(qkv_w, proj_w, wT, pT);
    qkv_attn<<<nwin * NHEAD / 4, 256, 0, stream>>>(x, mask, qkv_b, wT, attn);
    proj_gemm<<<(int)((nrows + 63) / 64), 256, 0, stream>>>(attn, pT, proj_b, out, nrows);
}

// Round 11
// 152.190 us; speedup vs baseline: 1.6545x; 1.6545x over previous
//
#include <hip/hip_runtime.h>

// WindowAttention fused kernel, MI355X gfx950 — round 11.
// Base = R3 (best verified: 135.5 us, absmax 9.8e-4), plus latency cuts:
//  - mask[b%64] staged to LDS in phase 1 (softmax's 64 global loads -> ds_reads)
//  - chunk-q B-frags preloaded before the stage barrier; chunk-k B-frags
//    prefetched inside chunk q's MFMA loop (rolling 48-VGPR window)
//  - v-chunk and proj B loads stay inline (keep VGPR <= ~160 -> 3 waves/SIMD)
// Numerics identical to R3/R8 (no-max softmax, unnormalized P, o*rinv at store).

#define DIMC 192
#define NHEAD 6
#define HD 32
#define NTOK 49
#define NWIN 64
#define SCALE 0.17677669529663687f  // 1/sqrt(32)

typedef short bf16x8 __attribute__((ext_vector_type(8)));
typedef short bf16x4 __attribute__((ext_vector_type(4)));
typedef short short4v __attribute__((ext_vector_type(4)));
typedef float f32x4 __attribute__((ext_vector_type(4)));

__device__ __forceinline__ short f2bs(float f) {
    // round-to-nearest-even fp32 -> bf16
    unsigned u = __builtin_bit_cast(unsigned, f);
    u = (u + 0x7fffu + ((u >> 16) & 1u)) >> 16;
    return (short)(unsigned short)u;
}

// 8-bf16 fragment load from 8B-aligned LDS
__device__ __forceinline__ bf16x8 ld8(const short* p) {
    bf16x4 lo = *reinterpret_cast<const bf16x4*>(p);
    bf16x4 hi = *reinterpret_cast<const bf16x4*>(p + 4);
    return __builtin_shufflevector(lo, hi, 0, 1, 2, 3, 4, 5, 6, 7);
}

__global__ void prep_weights(const float* __restrict__ qkv_w,
                             const float* __restrict__ proj_w,
                             short* __restrict__ wT, short* __restrict__ pT) {
    int i = blockIdx.x * 256 + threadIdx.x;
    if (i < DIMC * 3 * DIMC) {  // qkv_w [192][576] -> wT [576][192] bf16
        int k = i / (3 * DIMC), c = i - k * (3 * DIMC);
        wT[c * DIMC + k] = f2bs(qkv_w[i]);
    }
    if (i < DIMC * DIMC) {      // proj_w [192][192] -> pT [192][192] bf16 (transposed)
        int k = i / DIMC, c = i - k * DIMC;
        pT[c * DIMC + k] = f2bs(proj_w[i]);
    }
}

// LDS (shorts): xs [64][200] @ 0 (12800) ; per-wave scratch 2304 @ 12800 + wv*2304
//   scratch reuse: q [64][36] -> k [64][36] -> vT [32][72] -> P halves [64][36]
// mask fp32 [49][49] @ 26624 (4802 shorts)
// total 31426 shorts = 62852 B  => 2 blocks/CU

__global__ __launch_bounds__(384, 2)
void win_attn(const float* __restrict__ x, const float* __restrict__ mask,
              const float* __restrict__ qkv_b, const float* __restrict__ proj_b,
              const short* __restrict__ wT, const short* __restrict__ pT,
              float* __restrict__ out)
{
    __shared__ short smem[31426];
    short* const xs = smem;
    float* const mlds = reinterpret_cast<float*>(smem + 26624);

    const int b   = blockIdx.x;
    const int tid = threadIdx.x;
    const int wv  = tid >> 6;   // wave 0..5 == head
    const int ln  = tid & 63;
    const int lr  = ln & 15;
    const int lg  = ln >> 4;
    short* const buf = smem + 12800 + wv * 2304;
    const int h = wv;

    // ---------- preload chunk-q B-frags (independent of LDS/barrier) ----------
    bf16x8 bwq[12];
    #pragma unroll
    for (int kk = 0; kk < 6; ++kk)
        #pragma unroll
        for (int n = 0; n < 2; ++n)
            bwq[kk * 2 + n] = *reinterpret_cast<const bf16x8*>(
                &wT[(h * HD + n * 16 + lr) * DIMC + kk * 32 + lg * 8]);

    // ---------- Phase 1: stage x -> bf16 LDS + mask -> LDS ----------
    {
        const float4* xb4 = reinterpret_cast<const float4*>(x + (long)b * NTOK * DIMC);
        for (int i = tid; i < NTOK * (DIMC / 4); i += 384) {   // 2352 float4s
            const int r = i / (DIMC / 4), c4 = i - r * (DIMC / 4);
            const float4 v = xb4[i];
            short4v s4;
            s4[0] = f2bs(v.x); s4[1] = f2bs(v.y); s4[2] = f2bs(v.z); s4[3] = f2bs(v.w);
            *reinterpret_cast<short4v*>(&xs[r * 200 + c4 * 4]) = s4;
        }
        for (int i = tid; i < (64 - NTOK) * (DIMC / 4); i += 384) {
            const int r = NTOK + i / (DIMC / 4), c4 = i % (DIMC / 4);
            *reinterpret_cast<short4v*>(&xs[r * 200 + c4 * 4]) = short4v{0, 0, 0, 0};
        }
        const float* mrow = mask + (long)(b & (NWIN - 1)) * NTOK * NTOK;
        for (int i = tid; i < NTOK * NTOK; i += 384) mlds[i] = mrow[i];
    }
    __syncthreads();

    bf16x8 qa[4], kb[4], vb[2][2], bwk[12];

    // ---------- Phase 2: QKV (3 chunks), transposes via private buf ----------
    {
        f32x4 acc[4][2];

        // ---- chunk q: uses bwq, prefetches bwk ----
        #pragma unroll
        for (int m = 0; m < 4; ++m)
            #pragma unroll
            for (int n = 0; n < 2; ++n) acc[m][n] = f32x4{0.f, 0.f, 0.f, 0.f};
        __builtin_amdgcn_s_setprio(1);
        #pragma unroll
        for (int kk = 0; kk < 6; ++kk) {
            const int k0 = kk * 32 + lg * 8;
            bf16x8 a[4];
            #pragma unroll
            for (int m = 0; m < 4; ++m)
                a[m] = *reinterpret_cast<const bf16x8*>(&xs[(m * 16 + lr) * 200 + k0]);
            bwk[kk * 2 + 0] = *reinterpret_cast<const bf16x8*>(
                &wT[(DIMC + h * HD + lr) * DIMC + k0]);
            bwk[kk * 2 + 1] = *reinterpret_cast<const bf16x8*>(
                &wT[(DIMC + h * HD + 16 + lr) * DIMC + k0]);
            #pragma unroll
            for (int n = 0; n < 2; ++n)
                #pragma unroll
                for (int m = 0; m < 4; ++m)
                    acc[m][n] = __builtin_amdgcn_mfma_f32_16x16x32_bf16(a[m], bwq[kk * 2 + n], acc[m][n], 0, 0, 0);
        }
        __builtin_amdgcn_s_setprio(0);
        #pragma unroll
        for (int n2 = 0; n2 < 2; ++n2) {
            const float bias = qkv_b[h * HD + n2 * 16 + lr];
            #pragma unroll
            for (int m = 0; m < 4; ++m)
                #pragma unroll
                for (int r = 0; r < 4; ++r)
                    buf[(m * 16 + lg * 4 + r) * 36 + n2 * 16 + lr] = f2bs(acc[m][n2][r] + bias);
        }
        #pragma unroll
        for (int m = 0; m < 4; ++m)
            qa[m] = ld8(&buf[(m * 16 + lr) * 36 + lg * 8]);

        // ---- chunk k: uses bwk ----
        #pragma unroll
        for (int m = 0; m < 4; ++m)
            #pragma unroll
            for (int n = 0; n < 2; ++n) acc[m][n] = f32x4{0.f, 0.f, 0.f, 0.f};
        __builtin_amdgcn_s_setprio(1);
        #pragma unroll
        for (int kk = 0; kk < 6; ++kk) {
            const int k0 = kk * 32 + lg * 8;
            bf16x8 a[4];
            #pragma unroll
            for (int m = 0; m < 4; ++m)
                a[m] = *reinterpret_cast<const bf16x8*>(&xs[(m * 16 + lr) * 200 + k0]);
            #pragma unroll
            for (int n = 0; n < 2; ++n)
                #pragma unroll
                for (int m = 0; m < 4; ++m)
                    acc[m][n] = __builtin_amdgcn_mfma_f32_16x16x32_bf16(a[m], bwk[kk * 2 + n], acc[m][n], 0, 0, 0);
        }
        __builtin_amdgcn_s_setprio(0);
        #pragma unroll
        for (int n2 = 0; n2 < 2; ++n2) {
            const float bias = qkv_b[DIMC + h * HD + n2 * 16 + lr];
            #pragma unroll
            for (int m = 0; m < 4; ++m)
                #pragma unroll
                for (int r = 0; r < 4; ++r)
                    buf[(m * 16 + lg * 4 + r) * 36 + n2 * 16 + lr] = f2bs(acc[m][n2][r] + bias);
        }
        #pragma unroll
        for (int m = 0; m < 4; ++m)
            kb[m] = ld8(&buf[(m * 16 + lr) * 36 + lg * 8]);

        // ---- chunk v: inline B loads (R3 style) -> vT [32][72] ----
        #pragma unroll
        for (int m = 0; m < 4; ++m)
            #pragma unroll
            for (int n = 0; n < 2; ++n) acc[m][n] = f32x4{0.f, 0.f, 0.f, 0.f};
        __builtin_amdgcn_s_setprio(1);
        #pragma unroll
        for (int kk = 0; kk < 6; ++kk) {
            const int k0 = kk * 32 + lg * 8;
            bf16x8 a[4];
            #pragma unroll
            for (int m = 0; m < 4; ++m)
                a[m] = *reinterpret_cast<const bf16x8*>(&xs[(m * 16 + lr) * 200 + k0]);
            #pragma unroll
            for (int n = 0; n < 2; ++n) {
                bf16x8 bw = *reinterpret_cast<const bf16x8*>(
                    &wT[(2 * DIMC + h * HD + n * 16 + lr) * DIMC + k0]);
                #pragma unroll
                for (int m = 0; m < 4; ++m)
                    acc[m][n] = __builtin_amdgcn_mfma_f32_16x16x32_bf16(a[m], bw, acc[m][n], 0, 0, 0);
            }
        }
        __builtin_amdgcn_s_setprio(0);
        #pragma unroll
        for (int n2 = 0; n2 < 2; ++n2) {
            const float bias = qkv_b[2 * DIMC + h * HD + n2 * 16 + lr];
            #pragma unroll
            for (int m = 0; m < 4; ++m)
                #pragma unroll
                for (int r = 0; r < 4; ++r)
                    buf[(n2 * 16 + lr) * 72 + m * 16 + lg * 4 + r] = f2bs(acc[m][n2][r] + bias);
        }
        #pragma unroll
        for (int kk = 0; kk < 2; ++kk)
            #pragma unroll
            for (int nb = 0; nb < 2; ++nb)
                vb[kk][nb] = ld8(&buf[(nb * 16 + lr) * 72 + kk * 32 + lg * 8]);
    }

    // ---------- Phase 3: S = q k^T ----------
    f32x4 s[4][4];
    #pragma unroll
    for (int m = 0; m < 4; ++m)
        #pragma unroll
        for (int n = 0; n < 4; ++n) s[m][n] = f32x4{0.f, 0.f, 0.f, 0.f};
    __builtin_amdgcn_s_setprio(1);
    #pragma unroll
    for (int m = 0; m < 4; ++m)
        #pragma unroll
        for (int n = 0; n < 4; ++n)
            s[m][n] = __builtin_amdgcn_mfma_f32_16x16x32_bf16(qa[m], kb[n], s[m][n], 0, 0, 0);
    __builtin_amdgcn_s_setprio(0);

    // scale + mask(LDS) + softmax WITHOUT max-subtraction (logits bounded)
    float rinv[4][4];
    #pragma unroll
    for (int m = 0; m < 4; ++m)
        #pragma unroll
        for (int n = 0; n < 4; ++n) {
            const int col = n * 16 + lr;
            #pragma unroll
            for (int r = 0; r < 4; ++r) {
                const int row = m * 16 + lg * 4 + r;
                const bool valid = (row < NTOK) & (col < NTOK);
                const int mi = valid ? row * NTOK + col : 0;
                float v = valid ? s[m][n][r] * SCALE + mlds[mi] : -1e30f;
                s[m][n][r] = __expf(v);
            }
        }
    #pragma unroll
    for (int m = 0; m < 4; ++m)
        #pragma unroll
        for (int r = 0; r < 4; ++r) {
            float sum = s[m][0][r] + s[m][1][r] + s[m][2][r] + s[m][3][r];
            sum += __shfl_xor(sum, 1);
            sum += __shfl_xor(sum, 2);
            sum += __shfl_xor(sum, 4);
            sum += __shfl_xor(sum, 8);
            rinv[m][r] = 1.f / sum;
        }

    // ---------- Phase 4: PV via two UNNORMALIZED P halves in buf [64][36] ----------
    f32x4 o[4][2];
    #pragma unroll
    for (int m = 0; m < 4; ++m)
        #pragma unroll
        for (int n = 0; n < 2; ++n) o[m][n] = f32x4{0.f, 0.f, 0.f, 0.f};
    #pragma unroll
    for (int half = 0; half < 2; ++half) {
        #pragma unroll
        for (int m = 0; m < 4; ++m)
            #pragma unroll
            for (int n2 = 0; n2 < 2; ++n2)
                #pragma unroll
                for (int r = 0; r < 4; ++r)
                    buf[(m * 16 + lg * 4 + r) * 36 + n2 * 16 + lr] = f2bs(s[m][half * 2 + n2][r]);
        bf16x8 pa[4];
        #pragma unroll
        for (int mi = 0; mi < 4; ++mi)
            pa[mi] = ld8(&buf[(mi * 16 + lr) * 36 + lg * 8]);
        __builtin_amdgcn_s_setprio(1);
        #pragma unroll
        for (int nb = 0; nb < 2; ++nb)
            #pragma unroll
            for (int mi = 0; mi < 4; ++mi)
                o[mi][nb] = __builtin_amdgcn_mfma_f32_16x16x32_bf16(pa[mi], vb[half][nb], o[mi][nb], 0, 0, 0);
        __builtin_amdgcn_s_setprio(0);
    }

    __syncthreads();   // all waves done reading xs -> safe to overwrite with attn_out

    // normalize + write attn_out bf16 into xs [64][200] (cols h*32..h*32+31)
    #pragma unroll
    for (int nb = 0; nb < 2; ++nb)
        #pragma unroll
        for (int m = 0; m < 4; ++m)
            #pragma unroll
            for (int r = 0; r < 4; ++r) {
                const int row = m * 16 + lg * 4 + r;
                xs[row * 200 + h * HD + nb * 16 + lr] = f2bs(o[m][nb][r] * rinv[m][r]);
            }
    __syncthreads();

    // ---------- Phase 5: proj GEMM (wave wv -> out cols [wv*32, wv*32+32)) ----------
    {
        f32x4 acc2[4][2];
        #pragma unroll
        for (int m = 0; m < 4; ++m)
            #pragma unroll
            for (int n = 0; n < 2; ++n) acc2[m][n] = f32x4{0.f, 0.f, 0.f, 0.f};
        const int c0 = wv * 32;
        __builtin_amdgcn_s_setprio(1);
        #pragma unroll
        for (int kk = 0; kk < 6; ++kk) {
            const int k0 = kk * 32 + lg * 8;
            bf16x8 a[4];
            #pragma unroll
            for (int m = 0; m < 4; ++m)
                a[m] = *reinterpret_cast<const bf16x8*>(&xs[(m * 16 + lr) * 200 + k0]);
            #pragma unroll
            for (int n = 0; n < 2; ++n) {
                bf16x8 bw = *reinterpret_cast<const bf16x8*>(&pT[(c0 + n * 16 + lr) * DIMC + k0]);
                #pragma unroll
                for (int m = 0; m < 4; ++m)
                    acc2[m][n] = __builtin_amdgcn_mfma_f32_16x16x32_bf16(a[m], bw, acc2[m][n], 0, 0, 0);
            }
        }
        __builtin_amdgcn_s_setprio(0);
        float* ob = out + (long)b * NTOK * DIMC;
        #pragma unroll
        for (int n = 0; n < 2; ++n) {
            const int c = c0 + n * 16 + lr;
            const float pb = proj_b[c];
            #pragma unroll
            for (int m = 0; m < 4; ++m)
                #pragma unroll
                for (int r = 0; r < 4; ++r) {
                    const int row = m * 16 + lg * 4 + r;
                    if (row < NTOK) ob[row * DIMC + c] = acc2[m][n][r] + pb;
                }
        }
    }
}

extern "C" void kernel_launch(void* const* d_in, const int* in_sizes, int n_in,
                              void* d_out, int out_size, void* d_ws, size_t ws_size,
                              hipStream_t stream) {
    const float* x      = (const float*)d_in[0];
    const float* mask   = (const float*)d_in[1];
    const float* qkv_w  = (const float*)d_in[2];
    const float* qkv_b  = (const float*)d_in[3];
    const float* proj_w = (const float*)d_in[4];
    const float* proj_b = (const float*)d_in[5];
    float* out = (float*)d_out;

    short* wT = (short*)d_ws;                 // 576*192 bf16
    short* pT = wT + DIMC * 3 * DIMC;         // 192*192 bf16

    const int nwin = in_sizes[0] / (NTOK * DIMC);   // 2048

    prep_weights<<<(DIMC * 3 * DIMC + 255) / 256, 256, 0, stream>>>(qkv_w, proj_w, wT, pT);
    win_attn<<<nwin, 384, 0, stream>>>(x, mask, qkv_b, proj_b, wT, pT, out);
}